// Round 9
// baseline (1029.262 us; speedup 1.0000x reference)
//
#include <hip/hip_runtime.h>
#include <hip/hip_bf16.h>
#include <stdint.h>

// Problem constants (from reference)
#define T_TOK 4096
#define D_DIM 512
#define L_SPAN 10
#define H_DIM 512
#define N_SPAN 40960
#define K_TOP 1638      // int(0.4 * 4096)
#define CAND_CAP 6144   // candidate capacity for exact re-score
#define MARGIN 0.01f    // approx-score margin (bf16-path err ~0.002)

typedef __attribute__((ext_vector_type(8))) short bf16x8;
typedef __attribute__((ext_vector_type(4))) float f32x4;

__device__ __forceinline__ ushort f2bf(float x) {  // RNE float->bf16 bits
  uint32_t u = __float_as_uint(x);
  return (ushort)((u + 0x7FFFu + ((u >> 16) & 1u)) >> 16);
}
__device__ __forceinline__ float bf2f(ushort s) {
  return __uint_as_float(((uint32_t)s) << 16);
}

// Async global->LDS, 16B per lane. LDS dest must be wave-uniform base
// (HW writes lane l at base + l*16); global src is per-lane.
__device__ __forceinline__ void gload16(const void* g, void* l) {
  __builtin_amdgcn_global_load_lds(
      (const __attribute__((address_space(1))) uint32_t*)g,
      (__attribute__((address_space(3))) uint32_t*)l, 16, 0, 0);
}

// ---------------------------------------------------------------------------
// fp32 GEMM, small-tile high-occupancy (validated R8). C = relu(A@B + bias).
// BM=32, BN=64, BK=32, 256 thr, 2x4 micro-tile. Ascending-k fmaf chain ->
// bitwise identical to the validated numeric path for any tiling.
// INDEXED: A row = rowIdx[slot]; slots >= *rowCnt guarded to row 0.
// ---------------------------------------------------------------------------
template <bool RELU, bool INDEXED>
__global__ __launch_bounds__(256) void sgemm32(
    const float* __restrict__ A, const float* __restrict__ B,
    const float* __restrict__ bias, float* __restrict__ C,
    int Kk, int lda, int ldb, int ldc,
    const uint32_t* __restrict__ rowCnt, const int* __restrict__ rowIdx) {
  const int BM = 32, BN = 64, BK = 32;
  __shared__ float As[BK][BM + 2];
  __shared__ float Bs[BK][BN + 4];

  int tid = threadIdx.x;
  int bn = blockIdx.x, bm = blockIdx.y;

  int cc = INDEXED ? 0 : 0x7fffffff;
  if (rowCnt) {
    cc = (int)*rowCnt;
    if (cc > CAND_CAP) cc = CAND_CAP;
    if (bm * BM >= ((cc + 31) & ~31)) return;  // uniform per block
  }

  int tx = tid & 15, ty = tid >> 4;
  int a_m = tid >> 3;
  int a_k2 = tid & 7;
  int b_c4 = tid & 15;
  int b_kr = tid >> 4;

  int slot = bm * BM + a_m;
  const float* aRow;
  if (INDEXED) {
    int grow = (slot < cc) ? rowIdx[slot] : 0;
    aRow = A + (size_t)grow * lda;
  } else {
    aRow = A + (size_t)slot * lda;
  }
  const float* bPtr = B + (size_t)b_kr * ldb + bn * BN + b_c4 * 4;

  float acc[2][4];
#pragma unroll
  for (int i = 0; i < 2; ++i)
#pragma unroll
    for (int j = 0; j < 4; ++j) acc[i][j] = 0.f;

  for (int k0 = 0; k0 < Kk; k0 += BK) {
#pragma unroll
    for (int p = 0; p < 2; ++p) {
      float2 v = *(const float2*)(aRow + k0 + p * 16 + a_k2 * 2);
      As[p * 16 + a_k2 * 2 + 0][a_m] = v.x;
      As[p * 16 + a_k2 * 2 + 1][a_m] = v.y;
    }
#pragma unroll
    for (int p = 0; p < 2; ++p) {
      float4 v = *(const float4*)(bPtr + (size_t)(k0 + p * 16) * ldb);
      *(float4*)&Bs[b_kr + p * 16][b_c4 * 4] = v;
    }
    __syncthreads();

#pragma unroll
    for (int kk = 0; kk < BK; ++kk) {
      float2 a = *(const float2*)&As[kk][ty * 2];
      float4 b = *(const float4*)&Bs[kk][tx * 4];
      acc[0][0] = fmaf(a.x, b.x, acc[0][0]);
      acc[0][1] = fmaf(a.x, b.y, acc[0][1]);
      acc[0][2] = fmaf(a.x, b.z, acc[0][2]);
      acc[0][3] = fmaf(a.x, b.w, acc[0][3]);
      acc[1][0] = fmaf(a.y, b.x, acc[1][0]);
      acc[1][1] = fmaf(a.y, b.y, acc[1][1]);
      acc[1][2] = fmaf(a.y, b.z, acc[1][2]);
      acc[1][3] = fmaf(a.y, b.w, acc[1][3]);
    }
    __syncthreads();
  }

  int col0 = bn * BN + tx * 4;
  float4 bb = *(const float4*)(bias + col0);
#pragma unroll
  for (int i = 0; i < 2; ++i) {
    int row = bm * BM + ty * 2 + i;
    float o0 = acc[i][0] + bb.x;
    float o1 = acc[i][1] + bb.y;
    float o2 = acc[i][2] + bb.z;
    float o3 = acc[i][3] + bb.w;
    if (RELU) {
      o0 = fmaxf(o0, 0.f); o1 = fmaxf(o1, 0.f);
      o2 = fmaxf(o2, 0.f); o3 = fmaxf(o3, 0.f);
    }
    *(float4*)(C + (size_t)row * ldc + col0) = make_float4(o0, o1, o2, o3);
  }
}

// ---------------------------------------------------------------------------
// m97-style bf16 MFMA GEMM (R9): 128x128 tile, BK=32, 4 waves (2x2), 16
// MFMA/K-step/wave, global_load_lds width-16 staging, LDS [kb][row][8] 16B
// cells (2-way bank alias only). B pre-transposed: BbT[n][k]. N fixed 512.
// Grid 1280: xcd=o&7, s=o>>3, bn=s&3, p=(s>>2)*8+xcd (bijective) -> 4 bn of
// a panel consecutive per XCD -> A-panel + full W L2-resident.
// FUSE: layer-2 epilogue computes relu(acc+b2)*w3, 16-lane shfl reduce,
// one atomicAdd per row into scoresA (init'd to b3) -> no s2 materialization.
// Approx scores become atomic-order nondeterministic (~1e-5 << MARGIN/2);
// final output depends only on exact re-scores of the candidate superset.
// Frag mapping (16x16x32): A row=l&15,k=(l>>4)*8+j; B col=l&15 same k;
// C/D col=l&15,row=(l>>4)*4+r  [validated end-to-end R4-R8].
// ---------------------------------------------------------------------------
template <bool FUSE>
__global__ __launch_bounds__(256) void mfma128(
    const ushort* __restrict__ Ab,   // [M][K] bf16
    const ushort* __restrict__ BbT,  // [512][K] bf16 (transposed weights)
    const float* __restrict__ bias,  // [512]
    ushort* __restrict__ Out,        // !FUSE: [M][512] bf16
    const float* __restrict__ w3,    // FUSE
    float* __restrict__ scoresA,     // FUSE
    int K) {
  __shared__ __align__(16) ushort As[4][128][8];  // [kb][row][j]: k = kb*8+j
  __shared__ __align__(16) ushort Bs[4][128][8];  // [kb][col][j]

  int orig = blockIdx.x;
  int xcd = orig & 7;
  int s = orig >> 3;
  int bn = s & 3;
  int p = (s >> 2) * 8 + xcd;
  int rowbase = p * 128;
  int colbase = bn * 128;

  int tid = threadIdx.x;
  int w = tid >> 6, l = tid & 63;
  int waveM = w & 1, waveN = w >> 1;
  int lr = l & 15, lg = l >> 4;

  f32x4 acc[4][4];
#pragma unroll
  for (int m = 0; m < 4; ++m)
#pragma unroll
    for (int n = 0; n < 4; ++n)
#pragma unroll
      for (int r = 0; r < 4; ++r) acc[m][n][r] = 0.f;

  // Wave w stages kb=w for both A and B: 128 cells x 16B = 2 iters of 64.
  const ushort* gA = Ab + (size_t)rowbase * K + w * 8;
  const ushort* gB = BbT + (size_t)colbase * K + w * 8;

  for (int k0 = 0; k0 < K; k0 += 32) {
#pragma unroll
    for (int i = 0; i < 2; ++i) {
      int row = i * 64 + l;
      gload16(gA + (size_t)row * K + k0, &As[w][i * 64][0]);
      gload16(gB + (size_t)row * K + k0, &Bs[w][i * 64][0]);
    }
    __syncthreads();  // drains vmcnt(0): staged data visible

    bf16x8 af[4], bf[4];
#pragma unroll
    for (int m = 0; m < 4; ++m)
      af[m] = *(const bf16x8*)&As[lg][waveM * 64 + m * 16 + lr][0];
#pragma unroll
    for (int n = 0; n < 4; ++n)
      bf[n] = *(const bf16x8*)&Bs[lg][waveN * 64 + n * 16 + lr][0];
#pragma unroll
    for (int m = 0; m < 4; ++m)
#pragma unroll
      for (int n = 0; n < 4; ++n)
        acc[m][n] = __builtin_amdgcn_mfma_f32_16x16x32_bf16(af[m], bf[n], acc[m][n], 0, 0, 0);
    __syncthreads();  // protect LDS before next stage
  }

  if (FUSE) {
    float b2v[4], w3v[4];
#pragma unroll
    for (int n = 0; n < 4; ++n) {
      int cg = colbase + waveN * 64 + n * 16 + lr;
      b2v[n] = bias[cg];
      w3v[n] = w3[cg];
    }
#pragma unroll
    for (int m = 0; m < 4; ++m) {
#pragma unroll
      for (int r = 0; r < 4; ++r) {
        float v = 0.f;
#pragma unroll
        for (int n = 0; n < 4; ++n)
          v += fmaxf(acc[m][n][r] + b2v[n], 0.f) * w3v[n];
        v += __shfl_xor(v, 1);
        v += __shfl_xor(v, 2);
        v += __shfl_xor(v, 4);
        v += __shfl_xor(v, 8);
        if (lr == 0)
          atomicAdd(&scoresA[rowbase + waveM * 64 + m * 16 + lg * 4 + r], v);
      }
    }
  } else {
#pragma unroll
    for (int m = 0; m < 4; ++m) {
      int rg = rowbase + waveM * 64 + m * 16 + lg * 4;
#pragma unroll
      for (int n = 0; n < 4; ++n) {
        int cg = colbase + waveN * 64 + n * 16 + lr;
        float bb = bias[cg];
#pragma unroll
        for (int r = 0; r < 4; ++r) {
          float v = fmaxf(acc[m][n][r] + bb, 0.f);
          Out[(size_t)(rg + r) * 512 + cg] = f2bf(v);
        }
      }
    }
  }
}

// ---------------------------------------------------------------------------
// One-time weight prep: W[K][N] fp32 -> WT[N][K] bf16 (coalesced reads).
__global__ void cvt_transpose_kernel(const float* __restrict__ W,
                                     ushort* __restrict__ WT, int Kk, int Nn) {
  int i = blockIdx.x * blockDim.x + threadIdx.x;
  if (i < Kk * Nn) {
    int k = i / Nn, n = i % Nn;
    WT[(size_t)n * Kk + k] = f2bf(W[i]);
  }
}

__global__ void init_scores_kernel(float* __restrict__ scoresA,
                                   const float* __restrict__ b3) {
  int i = blockIdx.x * blockDim.x + threadIdx.x;
  if (i < N_SPAN) scoresA[i] = b3[0];
}

// Row dot fp32 (exact path). cnt != null: rows >= min(*cnt,CAND_CAP) skipped.
__global__ __launch_bounds__(256) void rowdot_kernel(
    const float* __restrict__ X, const float* __restrict__ w,
    const float* __restrict__ b, float* __restrict__ out, int rows,
    const uint32_t* __restrict__ cnt) {
  int gid = blockIdx.x * blockDim.x + threadIdx.x;
  int wave = gid >> 6;
  int lane = threadIdx.x & 63;
  if (wave >= rows) return;
  if (cnt) {
    int cc = (int)*cnt;
    if (cc > CAND_CAP) cc = CAND_CAP;
    if (wave >= cc) return;
  }
  const float* x = X + (size_t)wave * H_DIM;
  float s = 0.f;
#pragma unroll
  for (int i = 0; i < 8; ++i) s = fmaf(x[lane + i * 64], w[lane + i * 64], s);
#pragma unroll
  for (int off = 32; off > 0; off >>= 1) s += __shfl_down(s, off);
  if (lane == 0) out[wave] = s + b[0];
}

// ---------------------------------------------------------------------------
// Span kernel (fp32 path bit-matches validated chain). Also emits g_bf.
// ---------------------------------------------------------------------------
__global__ __launch_bounds__(256) void span_kernel(
    const float* __restrict__ states, const float* __restrict__ embeds,
    const int* __restrict__ starts, const int* __restrict__ widths,
    const float* __restrict__ attns, float* __restrict__ g,
    ushort* __restrict__ g_bf) {
  int n = blockIdx.x;
  int tid = threadIdx.x;
  int st = starts[n];
  int wd = widths[n];

  float w[L_SPAN];
  float mx = -1e30f;
#pragma unroll
  for (int l = 0; l < L_SPAN; ++l) {
    float a = attns[st + l];  // in-range: st+9 <= T-1
    a = (l <= wd) ? a : -1e30f;
    w[l] = a;
    mx = fmaxf(mx, a);
  }
  float ssum = 0.f;
#pragma unroll
  for (int l = 0; l < L_SPAN; ++l) {
    float e = expf(w[l] - mx);
    e = (l <= wd) ? e : 0.f;
    w[l] = e;
    ssum += e;
  }
  float inv = 1.f / ssum;

  int d = tid * 2;
  float2 att = make_float2(0.f, 0.f);
#pragma unroll
  for (int l = 0; l < L_SPAN; ++l) {
    float2 e = *(const float2*)(embeds + (size_t)(st + l) * D_DIM + d);
    float wl = w[l] * inv;
    att.x = fmaf(wl, e.x, att.x);
    att.y = fmaf(wl, e.y, att.y);
  }

  float* grow = g + (size_t)n * (3 * D_DIM);
  float2 s0 = *(const float2*)(states + (size_t)st * D_DIM + d);
  float2 s1 = *(const float2*)(states + (size_t)(st + wd) * D_DIM + d);
  *(float2*)(grow + d) = s0;
  *(float2*)(grow + D_DIM + d) = s1;
  *(float2*)(grow + 2 * D_DIM + d) = att;

  ushort* brow = g_bf + (size_t)n * (3 * D_DIM);
  *(ushort2*)(brow + d) = make_ushort2(f2bf(s0.x), f2bf(s0.y));
  *(ushort2*)(brow + D_DIM + d) = make_ushort2(f2bf(s1.x), f2bf(s1.y));
  *(ushort2*)(brow + 2 * D_DIM + d) = make_ushort2(f2bf(att.x), f2bf(att.y));
}

// ---------------------------------------------------------------------------
// Radix-select machinery on approx scores.
// meta: 0:b1 1:rem1 2:thr_key 3:need_eq 6:candCount
// ---------------------------------------------------------------------------
__global__ void keys_kernel(const float* __restrict__ scores, uint32_t* __restrict__ keys) {
  int n = blockIdx.x * blockDim.x + threadIdx.x;
  if (n < N_SPAN) {
    uint32_t u = __float_as_uint(scores[n]);
    keys[n] = (u & 0x80000000u) ? ~u : (u | 0x80000000u);
  }
}

__global__ void zero_kernel(uint32_t* __restrict__ p, int n) {
  int i = blockIdx.x * blockDim.x + threadIdx.x;
  if (i < n) p[i] = 0u;
}

__global__ void hist_hi_kernel(const uint32_t* __restrict__ keys, uint32_t* __restrict__ hist) {
  int n = blockIdx.x * blockDim.x + threadIdx.x;
  if (n < N_SPAN) atomicAdd(&hist[keys[n] >> 16], 1u);
}

__global__ void hist_lo_kernel(const uint32_t* __restrict__ keys,
                               const uint32_t* __restrict__ meta,
                               uint32_t* __restrict__ hist) {
  int n = blockIdx.x * blockDim.x + threadIdx.x;
  if (n < N_SPAN) {
    uint32_t k = keys[n];
    if ((k >> 16) == meta[0]) atomicAdd(&hist[k & 0xffffu], 1u);
  }
}

__global__ __launch_bounds__(1024) void select_kernel(
    const uint32_t* __restrict__ hist, uint32_t* __restrict__ meta, int level) {
  __shared__ uint32_t csum[1024];
  int tid = threadIdx.x;
  uint32_t Kwant = (level == 0) ? (uint32_t)K_TOP : meta[1];

  uint32_t s = 0;
  for (int j = 0; j < 64; ++j) s += hist[tid * 64 + j];
  csum[tid] = s;
  __syncthreads();
  for (int off = 1; off < 1024; off <<= 1) {
    uint32_t other = (tid + off < 1024) ? csum[tid + off] : 0u;
    __syncthreads();
    csum[tid] += other;
    __syncthreads();
  }
  if (csum[tid] >= Kwant && (tid == 1023 || csum[tid + 1] < Kwant)) {
    uint32_t running = (tid == 1023) ? 0u : csum[tid + 1];
    for (int j = 63; j >= 0; --j) {
      uint32_t h = hist[tid * 64 + j];
      if (running + h >= Kwant) {
        if (level == 0) {
          meta[0] = (uint32_t)(tid * 64 + j);
          meta[1] = Kwant - running;
        } else {
          meta[2] = (meta[0] << 16) | (uint32_t)(tid * 64 + j);
          meta[3] = Kwant - running;
        }
        break;
      }
      running += h;
    }
  }
}

// Candidates: approx key >= key(float(thr) - MARGIN).
__global__ void compact_cand(const uint32_t* __restrict__ keys, uint32_t* __restrict__ meta,
                             int* __restrict__ candIdx) {
  int n = blockIdx.x * blockDim.x + threadIdx.x;
  if (n >= N_SPAN) return;
  uint32_t tk = meta[2];
  uint32_t tu = (tk & 0x80000000u) ? (tk & 0x7FFFFFFFu) : ~tk;  // inverse key->bits
  float tf = __uint_as_float(tu) - MARGIN;
  uint32_t mu = __float_as_uint(tf);
  uint32_t mk = (mu & 0x80000000u) ? ~mu : (mu | 0x80000000u);
  if (keys[n] >= mk) {
    uint32_t p = atomicAdd(&meta[6], 1u);
    if (p < CAND_CAP) candIdx[p] = n;
  }
}

// ---------------------------------------------------------------------------
// Final: among candidates (exact fp32 scores), top-K_TOP with stable
// tie-break (lowest index first), then sort selected by index. One block.
// ---------------------------------------------------------------------------
__global__ __launch_bounds__(1024) void final_hybrid(
    const uint32_t* __restrict__ meta, const int* __restrict__ candIdx,
    const float* __restrict__ candExact,
    float* __restrict__ out_scores, float* __restrict__ out_idx) {
  __shared__ uint64_t pr[8192];  // 64 KB
  int tid = threadIdx.x;
  int C = (int)meta[6];
  if (C > CAND_CAP) C = CAND_CAP;

  for (int i = tid; i < 8192; i += 1024) {
    uint64_t inv = ~0ULL;  // pad sorts last
    if (i < C) {
      uint32_t u = __float_as_uint(candExact[i]);
      uint32_t k = (u & 0x80000000u) ? ~u : (u | 0x80000000u);
      uint32_t orig = (uint32_t)candIdx[i];
      uint32_t low = ((0xFFFFu - orig) << 13) | (uint32_t)i;
      inv = ~(((uint64_t)k << 32) | low);
    }
    pr[i] = inv;
  }
  __syncthreads();
  for (int kk = 2; kk <= 8192; kk <<= 1) {
    for (int j = kk >> 1; j > 0; j >>= 1) {
      for (int t = tid; t < 8192; t += 1024) {
        int ixj = t ^ j;
        if (ixj > t) {
          bool up = ((t & kk) == 0);
          uint64_t a = pr[t], b = pr[ixj];
          if ((a > b) == up) { pr[t] = b; pr[ixj] = a; }
        }
      }
      __syncthreads();
    }
  }
  uint64_t mine[2];
#pragma unroll
  for (int t = 0; t < 2; ++t) {
    int i = tid + t * 1024;
    uint64_t v = ~pr[i];
    uint32_t low = (uint32_t)v;
    uint32_t orig = 0xFFFFu - ((low >> 13) & 0xFFFFu);
    uint32_t slot = low & 0x1FFFu;
    mine[t] = (i < K_TOP) ? (((uint64_t)orig << 32) | slot) : ~0ULL;
  }
  __syncthreads();
  pr[tid] = mine[0];
  pr[tid + 1024] = mine[1];
  __syncthreads();
  for (int kk = 2; kk <= 2048; kk <<= 1) {
    for (int j = kk >> 1; j > 0; j >>= 1) {
      for (int t = tid; t < 2048; t += 1024) {
        int ixj = t ^ j;
        if (ixj > t) {
          bool up = ((t & kk) == 0);
          uint64_t a = pr[t], b = pr[ixj];
          if ((a > b) == up) { pr[t] = b; pr[ixj] = a; }
        }
      }
      __syncthreads();
    }
  }
  for (int i = tid; i < K_TOP; i += 1024) {
    uint64_t v = pr[i];
    out_idx[i] = (float)(uint32_t)(v >> 32);
    out_scores[i] = candExact[v & 0x1FFFu];
  }
}

// ---------------------------------------------------------------------------
extern "C" void kernel_launch(void* const* d_in, const int* in_sizes, int n_in,
                              void* d_out, int out_size, void* d_ws, size_t ws_size,
                              hipStream_t stream) {
  const float* states = (const float*)d_in[0];
  const float* embeds = (const float*)d_in[1];
  const int* starts = (const int*)d_in[2];
  const int* widths = (const int*)d_in[3];
  const float* W_a1 = (const float*)d_in[4];
  const float* b_a1 = (const float*)d_in[5];
  const float* W_a2 = (const float*)d_in[6];
  const float* b_a2 = (const float*)d_in[7];
  const float* w_a3 = (const float*)d_in[8];
  const float* b_a3 = (const float*)d_in[9];
  const float* W_s1 = (const float*)d_in[10];
  const float* b_s1 = (const float*)d_in[11];
  const float* W_s2 = (const float*)d_in[12];
  const float* b_s2 = (const float*)d_in[13];
  const float* w_s3 = (const float*)d_in[14];
  const float* b_s3 = (const float*)d_in[15];

  float* out = (float*)d_out;
  float* out_scores = out;
  float* g = out + K_TOP;
  float* out_idx = out + K_TOP + (size_t)N_SPAN * 3 * D_DIM;

  // Workspace (MiB offsets; peak ~162.5 MiB, layout lineage R6-R8):
  //   [0,120)   g_bf (span -> mfma1); dead after mfma1 ->
  //             scoresA [40] | keys [41] | hist+meta [42] | candIdx [43] |
  //             e1 [80,92) | e2 [92,104) | candExact [104]
  //   [120,160) h1 [120,128) h2 [128,136) attns [136] (dead pre-mfma1)
  //             -> s1b [120,160) (mfma1 out, mfma2 in)
  //   [160,163) W1T [160,161.5) W2T [162,162.5)  (live through mfma2)
  char* ws = (char*)d_ws;
  const size_t MB = 1024 * 1024;
  ushort* g_bf = (ushort*)(ws + 0);               // 120 MiB
  float* scoresA = (float*)(ws + 40 * MB);        // 160 KB (after g_bf dead)
  uint32_t* keys = (uint32_t*)(ws + 41 * MB);     // 160 KB
  uint32_t* hist = (uint32_t*)(ws + 42 * MB);     // 256 KB
  uint32_t* meta = hist + 65536;                  // 16 u32
  int* candIdx = (int*)(ws + 43 * MB);            // 24 KB
  float* e1 = (float*)(ws + 80 * MB);             // 12 MiB
  float* e2 = (float*)(ws + 92 * MB);             // 12 MiB
  float* candExact = (float*)(ws + 104 * MB);     // 24 KB
  float* h1 = (float*)(ws + 120 * MB);            // 8 MiB
  float* h2 = (float*)(ws + 128 * MB);            // 8 MiB
  float* attns = (float*)(ws + 136 * MB);         // 16 KB
  ushort* s1b = (ushort*)(ws + 120 * MB);         // 40 MiB (after h1/h2/attns dead)
  ushort* W1T = (ushort*)(ws + 160 * MB);         // 1.5 MiB  [512][1536]
  ushort* W2T = (ushort*)(ws + 162 * MB);         // 0.5 MiB  [512][512]

  // 0: weights -> transposed bf16 (for contiguous gload_lds B-staging)
  cvt_transpose_kernel<<<(3 * D_DIM * H_DIM) / 256, 256, 0, stream>>>(
      W_s1, W1T, 3 * D_DIM, H_DIM);
  cvt_transpose_kernel<<<(H_DIM * H_DIM) / 256, 256, 0, stream>>>(
      W_s2, W2T, H_DIM, H_DIM);

  // 1-3: attention MLP (fp32, bitwise = validated chain)
  sgemm32<true, false><<<dim3(H_DIM / 64, T_TOK / 32), 256, 0, stream>>>(
      states, W_a1, b_a1, h1, D_DIM, D_DIM, H_DIM, H_DIM, nullptr, nullptr);
  sgemm32<true, false><<<dim3(H_DIM / 64, T_TOK / 32), 256, 0, stream>>>(
      h1, W_a2, b_a2, h2, H_DIM, H_DIM, H_DIM, H_DIM, nullptr, nullptr);
  rowdot_kernel<<<T_TOK / 4, 256, 0, stream>>>(h2, w_a3, b_a3, attns, T_TOK, nullptr);

  // 4: span softmax + g assembly (fp32 -> d_out) + g_bf (bf16 -> ws)
  span_kernel<<<N_SPAN, 256, 0, stream>>>(states, embeds, starts, widths, attns, g, g_bf);

  // 5-7: approx mention MLP via MFMA; layer 2 fused with w3-dot
  mfma128<false><<<1280, 256, 0, stream>>>(
      g_bf, W1T, b_s1, s1b, nullptr, nullptr, 3 * D_DIM);
  init_scores_kernel<<<N_SPAN / 256, 256, 0, stream>>>(scoresA, b_s3);
  mfma128<true><<<1280, 256, 0, stream>>>(
      s1b, W2T, b_s2, nullptr, w_s3, scoresA, H_DIM);

  // 8: approx threshold via 2-level radix select
  keys_kernel<<<N_SPAN / 256, 256, 0, stream>>>(scoresA, keys);
  zero_kernel<<<(65536 + 16 + 255) / 256, 256, 0, stream>>>(hist, 65536 + 16);
  hist_hi_kernel<<<N_SPAN / 256, 256, 0, stream>>>(keys, hist);
  select_kernel<<<1, 1024, 0, stream>>>(hist, meta, 0);
  zero_kernel<<<65536 / 256, 256, 0, stream>>>(hist, 65536);
  hist_lo_kernel<<<N_SPAN / 256, 256, 0, stream>>>(keys, meta, hist);
  select_kernel<<<1, 1024, 0, stream>>>(hist, meta, 1);

  // 9-11: candidates -> exact fp32 re-score (bitwise = validated chain)
  compact_cand<<<N_SPAN / 256, 256, 0, stream>>>(keys, meta, candIdx);
  sgemm32<true, true><<<dim3(H_DIM / 64, CAND_CAP / 32), 256, 0, stream>>>(
      g, W_s1, b_s1, e1, 3 * D_DIM, 3 * D_DIM, H_DIM, H_DIM, meta + 6, candIdx);
  sgemm32<true, false><<<dim3(H_DIM / 64, CAND_CAP / 32), 256, 0, stream>>>(
      e1, W_s2, b_s2, e2, H_DIM, H_DIM, H_DIM, H_DIM, meta + 6, nullptr);
  rowdot_kernel<<<CAND_CAP / 4, 256, 0, stream>>>(e2, w_s3, b_s3, candExact, CAND_CAP, meta + 6);

  // 12: exact top-K among candidates + index sort + output
  final_hybrid<<<1, 1024, 0, stream>>>(meta, candIdx, candExact, out_scores, out_idx);
}